// Round 1
// baseline (6345.423 us; speedup 1.0000x reference)
//
#include <hip/hip_runtime.h>

// Persistent seq2seq LSTM kernel for MI355X (gfx950).
// Design (v2 — co-residency):
//  - 512 blocks x 512 threads (8 waves), M=16 batch rows per block. VGPR<=128
//    (__launch_bounds__(512,4)) + 30.7KB LDS -> TWO blocks co-resident per CU
//    (16 waves/CU). Blocks are fully independent (rows independent), so one
//    block's barrier-serialized GEMM phase hides under the other's elementwise
//    phase — previously MfmaUtil(19%) and VALUBusy(47%) were serialized by the
//    6-barrier/step structure at 1 block/CU (24% occupancy).
//  - Gate GEMM [16 x K] @ [K x 256] via mfma_f32_16x16x32_f16. Each wave owns a
//    32-wide slice of the 256 gate columns; weight B-fragments are converted
//    fp32->f16 once per phase and pinned in VGPRs (loop-invariant, ~104 VGPRs).
//  - Activations live in LDS panels, row-major [16][stride], layout matching the
//    MFMA A-fragment reads (16B aligned ds_read_b128).
//      p0 (stride 168): [x(8) | zeros(24) | h0_prev(64) | y_prev(64, dec only)]
//      p1 (stride 136): [h0(64) | h1_prev(64)]
//      p2 (stride 136): [h1(64) | h2_prev(64)]
//  - Gate preacts (fp32) round-trip through LDS gbuf [16][260] for the
//    cross-wave i/f/g/o exchange; c-state stays in fp32 registers (2/thread/layer).
//  - Elementwise spread over all 512 threads: 2 hidden units/thread
//    (em=tid>>5, eu=(tid&31)*2) — halves the per-block ew critical path.
//  - f16 storage + fp32 accumulate/state: measured absmax ~9.8e-4 < 4.08e-3 thr.

#define TT   512
#define DD   8
#define HH   64
#define MM   16
#define S0   168   // panel0 stride (f16), even, 336B row -> 16B aligned frags
#define S12  136   // panel1/2 stride
#define NP   260   // gbuf stride (f32): %4==0 (16B align), %8!=0 (bank spread)

typedef _Float16 half8  __attribute__((ext_vector_type(8)));
typedef _Float16 half2t __attribute__((ext_vector_type(2)));
typedef float    floatx4 __attribute__((ext_vector_type(4)));
typedef float    floatx2 __attribute__((ext_vector_type(2)));

__device__ __forceinline__ float sigf(float x) {
    // 1/(1+e^-x); v_exp + v_rcp. Saturates correctly at +-inf.
    return __builtin_amdgcn_rcpf(1.0f + __expf(-x));
}
__device__ __forceinline__ float tanhfast(float x) {
    // 1 - 2/(1+e^{2x}); exact at 0, saturates to +-1.
    return 1.0f - 2.0f * __builtin_amdgcn_rcpf(1.0f + __expf(2.0f * x));
}

// B-fragment loader for layers 1/2: panel k: [0,64)=Wih cols, [64,128)=Whh cols
__device__ __forceinline__ half8 ldfrag_l12(const float* Wih, const float* Whh,
                                            int n, int s) {
    const float* src = (s < HH) ? (Wih + n * HH + s) : (Whh + n * HH + (s - HH));
    half8 r;
#pragma unroll
    for (int j = 0; j < 8; ++j) r[j] = (_Float16)src[j];
    return r;
}

// B-fragment loader for layer 0 (enc kih=8, dec kih=72):
// panel k: [0,8)=Wih x-cols, [8,32)=zeros, [32,96)=Whh, [96,160)=Wih y-cols(8..71)
__device__ __forceinline__ half8 ldfrag_l0(const float* Wih, int kih,
                                           const float* Whh, int n, int s) {
    half8 r;
    const float* src = nullptr;
    if (s < 8)        src = Wih + n * kih + s;
    else if (s < 32)  src = nullptr;
    else if (s < 96)  src = Whh + n * HH + (s - 32);
    else              src = Wih + n * kih + (s - 88);
    if (src) {
#pragma unroll
        for (int j = 0; j < 8; ++j) r[j] = (_Float16)src[j];
    } else {
#pragma unroll
        for (int j = 0; j < 8; ++j) r[j] = (_Float16)0.f;
    }
    return r;
}

// One layer's gate GEMM: acc(bias-init) += A(panel) * Wf; scatter preacts to gbuf.
// M=16 -> single m-tile: A rows l15, cols kt*32+q*8.
template <int KT, int KW>
__device__ __forceinline__ void gemm_layer(const _Float16* panel, int stride,
                                           const half8 (&wf)[KW][2],
                                           const float (&br)[2], float* gb,
                                           int l15, int q, int nbase) {
    floatx4 acc[2];
#pragma unroll
    for (int nt = 0; nt < 2; ++nt)
        acc[nt] = (floatx4){br[nt], br[nt], br[nt], br[nt]};
#pragma unroll
    for (int kt = 0; kt < KT; ++kt) {
        half8 a0 = *(const half8*)(panel + l15 * stride + kt * 32 + q * 8);
        acc[0] = __builtin_amdgcn_mfma_f32_16x16x32_f16(a0, wf[kt][0], acc[0], 0, 0, 0);
        acc[1] = __builtin_amdgcn_mfma_f32_16x16x32_f16(a0, wf[kt][1], acc[1], 0, 0, 0);
    }
    // C/D layout: col=lane&15, row=(lane>>4)*4+reg  [HW-verified mapping]
#pragma unroll
    for (int nt = 0; nt < 2; ++nt) {
        const int n = nbase + nt * 16 + l15;
#pragma unroll
        for (int r = 0; r < 4; ++r)
            gb[(q * 4 + r) * NP + n] = acc[nt][r];
    }
}

// Elementwise LSTM cell update for this thread's 2 hidden units (one m-row).
__device__ __forceinline__ void ew_layer(const float* g, float (&c)[2],
                                         _Float16* h0dst, _Float16* h1dst) {
    floatx2 gi = *(const floatx2*)(g);
    floatx2 gf = *(const floatx2*)(g + 64);
    floatx2 gg = *(const floatx2*)(g + 128);
    floatx2 go = *(const floatx2*)(g + 192);
    half2t h2;
#pragma unroll
    for (int j = 0; j < 2; ++j) {
        float iv = sigf(gi[j]);
        float fv = sigf(gf[j]);
        float gv = tanhfast(gg[j]);
        float ov = sigf(go[j]);
        float cv = fv * c[j] + iv * gv;
        c[j] = cv;
        h2[j] = (_Float16)(ov * tanhfast(cv));
    }
    *(half2t*)h0dst = h2;
    if (h1dst) *(half2t*)h1dst = h2;
}

__global__ __launch_bounds__(512, 4) void seq2seq_kernel(
    const float* __restrict__ encx, const float* __restrict__ decx,
    const float* __restrict__ eW0i, const float* __restrict__ eW0h, const float* __restrict__ eb0,
    const float* __restrict__ eW1i, const float* __restrict__ eW1h, const float* __restrict__ eb1,
    const float* __restrict__ eW2i, const float* __restrict__ eW2h, const float* __restrict__ eb2,
    const float* __restrict__ dW0i, const float* __restrict__ dW0h, const float* __restrict__ db0,
    const float* __restrict__ dW1i, const float* __restrict__ dW1h, const float* __restrict__ db1,
    const float* __restrict__ dW2i, const float* __restrict__ dW2h, const float* __restrict__ db2,
    const float* __restrict__ fcW, const float* __restrict__ fcb,
    float* __restrict__ out) {
    __shared__ _Float16 p0[MM * S0];
    __shared__ _Float16 p1[MM * S12];
    __shared__ _Float16 p2[MM * S12];
    __shared__ float gbuf[MM * NP];

    const int tid  = threadIdx.x;
    const int lane = tid & 63;
    const int wave = tid >> 6;
    const int l15  = lane & 15;
    const int q    = lane >> 4;
    const int nbase = wave * 32;          // this wave's gate-column slice
    const int rbase = blockIdx.x * MM;    // batch rows [rbase, rbase+16)

    const int em = tid >> 5;              // elementwise row 0..15
    const int eu = (tid & 31) * 2;        // elementwise unit base 0..62

    for (int i = tid; i < MM * S0; i += 512)  p0[i] = (_Float16)0.f;
    for (int i = tid; i < MM * S12; i += 512) p1[i] = (_Float16)0.f;
    for (int i = tid; i < MM * S12; i += 512) p2[i] = (_Float16)0.f;

    float c0[2] = {0, 0}, c1[2] = {0, 0}, c2[2] = {0, 0};

    // ---------------- encoder weight fragments (registers) ----------------
    half8 w0[5][2], w1[4][2], w2[4][2];
    float b0r[2], b1r[2], b2r[2];
#pragma unroll
    for (int nt = 0; nt < 2; ++nt) {
        const int n = nbase + nt * 16 + l15;
#pragma unroll
        for (int kt = 0; kt < 3; ++kt) w0[kt][nt] = ldfrag_l0(eW0i, 8, eW0h, n, kt * 32 + q * 8);
#pragma unroll
        for (int kt = 0; kt < 4; ++kt) w1[kt][nt] = ldfrag_l12(eW1i, eW1h, n, kt * 32 + q * 8);
#pragma unroll
        for (int kt = 0; kt < 4; ++kt) w2[kt][nt] = ldfrag_l12(eW2i, eW2h, n, kt * 32 + q * 8);
        b0r[nt] = eb0[n]; b1r[nt] = eb1[n]; b2r[nt] = eb2[n];
    }

    const int xrow = tid >> 3;  // 0..15 (valid when tid<128)
    const int xcol = tid & 7;
    float xr = 0.f;
    if (tid < 128) xr = encx[(size_t)(rbase + xrow) * TT * DD + xcol];

    _Float16* h0w = p0 + em * S0 + 32 + eu;
    _Float16* x1w = p1 + em * S12 + eu;
    _Float16* h1w = p1 + em * S12 + 64 + eu;
    _Float16* x2w = p2 + em * S12 + eu;
    _Float16* h2w = p2 + em * S12 + 64 + eu;
    _Float16* yw  = p0 + em * S0 + 96 + eu;
    float* gme = gbuf + em * NP + eu;

    __syncthreads();

    // ---------------- encoder loop ----------------
    for (int t = 0; t < TT; ++t) {
        if (tid < 128) p0[xrow * S0 + xcol] = (_Float16)xr;
        __syncthreads();  // B0: x_t + prev-step h writes visible
        if (tid < 128 && t + 1 < TT)
            xr = encx[(size_t)(rbase + xrow) * TT * DD + (t + 1) * DD + xcol];
        gemm_layer<3>(p0, S0, w0, b0r, gbuf, l15, q, nbase);
        __syncthreads();  // B1: gates visible
        ew_layer(gme, c0, h0w, x1w);
        __syncthreads();  // B2: h0 visible
        gemm_layer<4>(p1, S12, w1, b1r, gbuf, l15, q, nbase);
        __syncthreads();  // B3
        ew_layer(gme, c1, h1w, x2w);
        __syncthreads();  // B4
        gemm_layer<4>(p2, S12, w2, b2r, gbuf, l15, q, nbase);
        __syncthreads();  // B5
        ew_layer(gme, c2, h2w, nullptr);
        // no barrier: next-iter B0 fences h2 before any reader (gemm2 @ t+1)
    }

    __syncthreads();

    // ---------------- decoder weight fragments ----------------
#pragma unroll
    for (int nt = 0; nt < 2; ++nt) {
        const int n = nbase + nt * 16 + l15;
#pragma unroll
        for (int kt = 0; kt < 5; ++kt) w0[kt][nt] = ldfrag_l0(dW0i, 72, dW0h, n, kt * 32 + q * 8);
#pragma unroll
        for (int kt = 0; kt < 4; ++kt) w1[kt][nt] = ldfrag_l12(dW1i, dW1h, n, kt * 32 + q * 8);
#pragma unroll
        for (int kt = 0; kt < 4; ++kt) w2[kt][nt] = ldfrag_l12(dW2i, dW2h, n, kt * 32 + q * 8);
        b0r[nt] = db0[n]; b1r[nt] = db1[n]; b2r[nt] = db2[n];
    }
    half8 fw[2];
    const float fbr = (l15 < 8) ? fcb[l15] : 0.f;
#pragma unroll
    for (int kt = 0; kt < 2; ++kt) {
        half8 r;
        if (l15 < 8) {
            const float* s = fcW + l15 * HH + kt * 32 + q * 8;
#pragma unroll
            for (int j = 0; j < 8; ++j) r[j] = (_Float16)s[j];
        } else {
#pragma unroll
            for (int j = 0; j < 8; ++j) r[j] = (_Float16)0.f;
        }
        fw[kt] = r;
    }

    // y_prev(=0) init; x-pad cols of p0 still zero from kernel init
    *(half2t*)yw = (half2t){(_Float16)0.f, (_Float16)0.f};
    if (tid < 128) xr = decx[(size_t)(rbase + xrow) * TT * DD + xcol];

    // ---------------- decoder loop ----------------
    for (int t = 0; t < TT; ++t) {
        if (tid < 128) p0[xrow * S0 + xcol] = (_Float16)xr;
        __syncthreads();  // B0
        if (tid < 128 && t + 1 < TT)
            xr = decx[(size_t)(rbase + xrow) * TT * DD + (t + 1) * DD + xcol];
        gemm_layer<5>(p0, S0, w0, b0r, gbuf, l15, q, nbase);
        __syncthreads();  // B1
        ew_layer(gme, c0, h0w, x1w);
        __syncthreads();  // B2
        gemm_layer<4>(p1, S12, w1, b1r, gbuf, l15, q, nbase);
        __syncthreads();  // B3
        ew_layer(gme, c1, h1w, x2w);
        __syncthreads();  // B4
        gemm_layer<4>(p2, S12, w2, b2r, gbuf, l15, q, nbase);
        __syncthreads();  // B5
        ew_layer(gme, c2, h2w, yw);   // h2 -> panel2 h-slot AND p0 y_prev slot
        __syncthreads();  // B6: h2 visible for FC
        if (wave == 0) {
            floatx4 fa = (floatx4){fbr, fbr, fbr, fbr};
#pragma unroll
            for (int kt = 0; kt < 2; ++kt) {
                half8 a = *(const half8*)(p2 + l15 * S12 + 64 + kt * 32 + q * 8);
                fa = __builtin_amdgcn_mfma_f32_16x16x32_f16(a, fw[kt], fa, 0, 0, 0);
            }
            if (l15 < 8) {
#pragma unroll
                for (int r = 0; r < 4; ++r)
                    out[(size_t)(rbase + q * 4 + r) * TT * DD + (size_t)t * DD + l15] = fa[r];
            }
        }
        // FC reads fenced from next ew2-write by B0'..B5'; other waves wait at B0'
    }
}

extern "C" void kernel_launch(void* const* d_in, const int* in_sizes, int n_in,
                              void* d_out, int out_size, void* d_ws, size_t ws_size,
                              hipStream_t stream) {
    const float* encx = (const float*)d_in[0];
    const float* decx = (const float*)d_in[1];
    const float* eW0i = (const float*)d_in[2];
    const float* eW0h = (const float*)d_in[3];
    const float* eb0  = (const float*)d_in[4];
    const float* eW1i = (const float*)d_in[5];
    const float* eW1h = (const float*)d_in[6];
    const float* eb1  = (const float*)d_in[7];
    const float* eW2i = (const float*)d_in[8];
    const float* eW2h = (const float*)d_in[9];
    const float* eb2  = (const float*)d_in[10];
    const float* dW0i = (const float*)d_in[11];
    const float* dW0h = (const float*)d_in[12];
    const float* db0  = (const float*)d_in[13];
    const float* dW1i = (const float*)d_in[14];
    const float* dW1h = (const float*)d_in[15];
    const float* db1  = (const float*)d_in[16];
    const float* dW2i = (const float*)d_in[17];
    const float* dW2h = (const float*)d_in[18];
    const float* db2  = (const float*)d_in[19];
    const float* fcW  = (const float*)d_in[20];
    const float* fcb  = (const float*)d_in[21];
    float* out = (float*)d_out;

    seq2seq_kernel<<<dim3(512), dim3(512), 0, stream>>>(
        encx, decx, eW0i, eW0h, eb0, eW1i, eW1h, eb1, eW2i, eW2h, eb2,
        dW0i, dW0h, db0, dW1i, dW1h, db1, dW2i, dW2h, db2, fcW, fcb, out);
}

// Round 2
// 4235.861 us; speedup vs baseline: 1.4980x; 1.4980x over previous
//
#include <hip/hip_runtime.h>

// Persistent seq2seq LSTM kernel for MI355X (gfx950).
// Design (v3 — co-residency, fixed launch_bounds):
//  - 512 blocks x 512 threads (8 waves), M=16 batch rows per block. Blocks are
//    fully independent (rows independent), so one block's barrier-serialized
//    GEMM phase hides under the co-resident block's elementwise phase.
//  - __launch_bounds__(512, 2): hipcc treats arg2 with CUDA semantics = min
//    BLOCKS per CU. (512,4) forced 32 waves/CU -> 64-VGPR cap -> weight
//    fragments spilled to scratch (7.3 GB FETCH, 1.7x regression, measured).
//    (512,2) -> 16 waves/CU -> 128-VGPR cap; M=16 register demand ~110 fits.
//  - Gate GEMM [16 x K] @ [K x 256] via mfma_f32_16x16x32_f16. Each wave owns a
//    32-wide slice of the 256 gate columns; weight B-fragments are converted
//    fp32->f16 once per phase and pinned in VGPRs (loop-invariant, ~104 VGPRs).
//  - Activations live in LDS panels, row-major [16][stride], layout matching the
//    MFMA A-fragment reads (16B aligned ds_read_b128).
//      p0 (stride 168): [x(8) | zeros(24) | h0_prev(64) | y_prev(64, dec only)]
//      p1 (stride 136): [h0(64) | h1_prev(64)]
//      p2 (stride 136): [h1(64) | h2_prev(64)]
//  - Gate preacts (fp32) round-trip through LDS gbuf [16][260] for the
//    cross-wave i/f/g/o exchange; c-state stays in fp32 registers (2/thread/layer).
//  - Elementwise spread over all 512 threads: 2 hidden units/thread.
//  - f16 storage + fp32 accumulate/state: measured absmax ~9.8e-4 < 4.08e-3 thr.

#define TT   512
#define DD   8
#define HH   64
#define MM   16
#define S0   168   // panel0 stride (f16), even, 336B row -> 16B aligned frags
#define S12  136   // panel1/2 stride
#define NP   260   // gbuf stride (f32): %4==0 (16B align), %8!=0 (bank spread)

typedef _Float16 half8  __attribute__((ext_vector_type(8)));
typedef _Float16 half2t __attribute__((ext_vector_type(2)));
typedef float    floatx4 __attribute__((ext_vector_type(4)));
typedef float    floatx2 __attribute__((ext_vector_type(2)));

__device__ __forceinline__ float sigf(float x) {
    // 1/(1+e^-x); v_exp + v_rcp. Saturates correctly at +-inf.
    return __builtin_amdgcn_rcpf(1.0f + __expf(-x));
}
__device__ __forceinline__ float tanhfast(float x) {
    // 1 - 2/(1+e^{2x}); exact at 0, saturates to +-1.
    return 1.0f - 2.0f * __builtin_amdgcn_rcpf(1.0f + __expf(2.0f * x));
}

// B-fragment loader for layers 1/2: panel k: [0,64)=Wih cols, [64,128)=Whh cols
__device__ __forceinline__ half8 ldfrag_l12(const float* Wih, const float* Whh,
                                            int n, int s) {
    const float* src = (s < HH) ? (Wih + n * HH + s) : (Whh + n * HH + (s - HH));
    half8 r;
#pragma unroll
    for (int j = 0; j < 8; ++j) r[j] = (_Float16)src[j];
    return r;
}

// B-fragment loader for layer 0 (enc kih=8, dec kih=72):
// panel k: [0,8)=Wih x-cols, [8,32)=zeros, [32,96)=Whh, [96,160)=Wih y-cols(8..71)
__device__ __forceinline__ half8 ldfrag_l0(const float* Wih, int kih,
                                           const float* Whh, int n, int s) {
    half8 r;
    const float* src = nullptr;
    if (s < 8)        src = Wih + n * kih + s;
    else if (s < 32)  src = nullptr;
    else if (s < 96)  src = Whh + n * HH + (s - 32);
    else              src = Wih + n * kih + (s - 88);
    if (src) {
#pragma unroll
        for (int j = 0; j < 8; ++j) r[j] = (_Float16)src[j];
    } else {
#pragma unroll
        for (int j = 0; j < 8; ++j) r[j] = (_Float16)0.f;
    }
    return r;
}

// One layer's gate GEMM: acc(bias-init) += A(panel) * Wf; scatter preacts to gbuf.
// M=16 -> single m-tile: A rows l15, cols kt*32+q*8.
template <int KT, int KW>
__device__ __forceinline__ void gemm_layer(const _Float16* panel, int stride,
                                           const half8 (&wf)[KW][2],
                                           const float (&br)[2], float* gb,
                                           int l15, int q, int nbase) {
    floatx4 acc[2];
#pragma unroll
    for (int nt = 0; nt < 2; ++nt)
        acc[nt] = (floatx4){br[nt], br[nt], br[nt], br[nt]};
#pragma unroll
    for (int kt = 0; kt < KT; ++kt) {
        half8 a0 = *(const half8*)(panel + l15 * stride + kt * 32 + q * 8);
        acc[0] = __builtin_amdgcn_mfma_f32_16x16x32_f16(a0, wf[kt][0], acc[0], 0, 0, 0);
        acc[1] = __builtin_amdgcn_mfma_f32_16x16x32_f16(a0, wf[kt][1], acc[1], 0, 0, 0);
    }
    // C/D layout: col=lane&15, row=(lane>>4)*4+reg  [HW-verified mapping]
#pragma unroll
    for (int nt = 0; nt < 2; ++nt) {
        const int n = nbase + nt * 16 + l15;
#pragma unroll
        for (int r = 0; r < 4; ++r)
            gb[(q * 4 + r) * NP + n] = acc[nt][r];
    }
}

// Elementwise LSTM cell update for this thread's 2 hidden units (one m-row).
__device__ __forceinline__ void ew_layer(const float* g, float (&c)[2],
                                         _Float16* h0dst, _Float16* h1dst) {
    floatx2 gi = *(const floatx2*)(g);
    floatx2 gf = *(const floatx2*)(g + 64);
    floatx2 gg = *(const floatx2*)(g + 128);
    floatx2 go = *(const floatx2*)(g + 192);
    half2t h2;
#pragma unroll
    for (int j = 0; j < 2; ++j) {
        float iv = sigf(gi[j]);
        float fv = sigf(gf[j]);
        float gv = tanhfast(gg[j]);
        float ov = sigf(go[j]);
        float cv = fv * c[j] + iv * gv;
        c[j] = cv;
        h2[j] = (_Float16)(ov * tanhfast(cv));
    }
    *(half2t*)h0dst = h2;
    if (h1dst) *(half2t*)h1dst = h2;
}

__global__ __launch_bounds__(512, 2) void seq2seq_kernel(
    const float* __restrict__ encx, const float* __restrict__ decx,
    const float* __restrict__ eW0i, const float* __restrict__ eW0h, const float* __restrict__ eb0,
    const float* __restrict__ eW1i, const float* __restrict__ eW1h, const float* __restrict__ eb1,
    const float* __restrict__ eW2i, const float* __restrict__ eW2h, const float* __restrict__ eb2,
    const float* __restrict__ dW0i, const float* __restrict__ dW0h, const float* __restrict__ db0,
    const float* __restrict__ dW1i, const float* __restrict__ dW1h, const float* __restrict__ db1,
    const float* __restrict__ dW2i, const float* __restrict__ dW2h, const float* __restrict__ db2,
    const float* __restrict__ fcW, const float* __restrict__ fcb,
    float* __restrict__ out) {
    __shared__ _Float16 p0[MM * S0];
    __shared__ _Float16 p1[MM * S12];
    __shared__ _Float16 p2[MM * S12];
    __shared__ float gbuf[MM * NP];

    const int tid  = threadIdx.x;
    const int lane = tid & 63;
    const int wave = tid >> 6;
    const int l15  = lane & 15;
    const int q    = lane >> 4;
    const int nbase = wave * 32;          // this wave's gate-column slice
    const int rbase = blockIdx.x * MM;    // batch rows [rbase, rbase+16)

    const int em = tid >> 5;              // elementwise row 0..15
    const int eu = (tid & 31) * 2;        // elementwise unit base 0..62

    for (int i = tid; i < MM * S0; i += 512)  p0[i] = (_Float16)0.f;
    for (int i = tid; i < MM * S12; i += 512) p1[i] = (_Float16)0.f;
    for (int i = tid; i < MM * S12; i += 512) p2[i] = (_Float16)0.f;

    float c0[2] = {0, 0}, c1[2] = {0, 0}, c2[2] = {0, 0};

    // ---------------- encoder weight fragments (registers) ----------------
    half8 w0[5][2], w1[4][2], w2[4][2];
    float b0r[2], b1r[2], b2r[2];
#pragma unroll
    for (int nt = 0; nt < 2; ++nt) {
        const int n = nbase + nt * 16 + l15;
#pragma unroll
        for (int kt = 0; kt < 3; ++kt) w0[kt][nt] = ldfrag_l0(eW0i, 8, eW0h, n, kt * 32 + q * 8);
#pragma unroll
        for (int kt = 0; kt < 4; ++kt) w1[kt][nt] = ldfrag_l12(eW1i, eW1h, n, kt * 32 + q * 8);
#pragma unroll
        for (int kt = 0; kt < 4; ++kt) w2[kt][nt] = ldfrag_l12(eW2i, eW2h, n, kt * 32 + q * 8);
        b0r[nt] = eb0[n]; b1r[nt] = eb1[n]; b2r[nt] = eb2[n];
    }

    const int xrow = tid >> 3;  // 0..15 (valid when tid<128)
    const int xcol = tid & 7;
    float xr = 0.f;
    if (tid < 128) xr = encx[(size_t)(rbase + xrow) * TT * DD + xcol];

    _Float16* h0w = p0 + em * S0 + 32 + eu;
    _Float16* x1w = p1 + em * S12 + eu;
    _Float16* h1w = p1 + em * S12 + 64 + eu;
    _Float16* x2w = p2 + em * S12 + eu;
    _Float16* h2w = p2 + em * S12 + 64 + eu;
    _Float16* yw  = p0 + em * S0 + 96 + eu;
    float* gme = gbuf + em * NP + eu;

    __syncthreads();

    // ---------------- encoder loop ----------------
    for (int t = 0; t < TT; ++t) {
        if (tid < 128) p0[xrow * S0 + xcol] = (_Float16)xr;
        __syncthreads();  // B0: x_t + prev-step h writes visible
        if (tid < 128 && t + 1 < TT)
            xr = encx[(size_t)(rbase + xrow) * TT * DD + (t + 1) * DD + xcol];
        gemm_layer<3>(p0, S0, w0, b0r, gbuf, l15, q, nbase);
        __syncthreads();  // B1: gates visible
        ew_layer(gme, c0, h0w, x1w);
        __syncthreads();  // B2: h0 visible
        gemm_layer<4>(p1, S12, w1, b1r, gbuf, l15, q, nbase);
        __syncthreads();  // B3
        ew_layer(gme, c1, h1w, x2w);
        __syncthreads();  // B4
        gemm_layer<4>(p2, S12, w2, b2r, gbuf, l15, q, nbase);
        __syncthreads();  // B5
        ew_layer(gme, c2, h2w, nullptr);
        // no barrier: next-iter B0 fences h2 before any reader (gemm2 @ t+1)
    }

    __syncthreads();

    // ---------------- decoder weight fragments ----------------
#pragma unroll
    for (int nt = 0; nt < 2; ++nt) {
        const int n = nbase + nt * 16 + l15;
#pragma unroll
        for (int kt = 0; kt < 5; ++kt) w0[kt][nt] = ldfrag_l0(dW0i, 72, dW0h, n, kt * 32 + q * 8);
#pragma unroll
        for (int kt = 0; kt < 4; ++kt) w1[kt][nt] = ldfrag_l12(dW1i, dW1h, n, kt * 32 + q * 8);
#pragma unroll
        for (int kt = 0; kt < 4; ++kt) w2[kt][nt] = ldfrag_l12(dW2i, dW2h, n, kt * 32 + q * 8);
        b0r[nt] = db0[n]; b1r[nt] = db1[n]; b2r[nt] = db2[n];
    }
    half8 fw[2];
    const float fbr = (l15 < 8) ? fcb[l15] : 0.f;
#pragma unroll
    for (int kt = 0; kt < 2; ++kt) {
        half8 r;
        if (l15 < 8) {
            const float* s = fcW + l15 * HH + kt * 32 + q * 8;
#pragma unroll
            for (int j = 0; j < 8; ++j) r[j] = (_Float16)s[j];
        } else {
#pragma unroll
            for (int j = 0; j < 8; ++j) r[j] = (_Float16)0.f;
        }
        fw[kt] = r;
    }

    // y_prev(=0) init; x-pad cols of p0 still zero from kernel init
    *(half2t*)yw = (half2t){(_Float16)0.f, (_Float16)0.f};
    if (tid < 128) xr = decx[(size_t)(rbase + xrow) * TT * DD + xcol];

    // ---------------- decoder loop ----------------
    for (int t = 0; t < TT; ++t) {
        if (tid < 128) p0[xrow * S0 + xcol] = (_Float16)xr;
        __syncthreads();  // B0
        if (tid < 128 && t + 1 < TT)
            xr = decx[(size_t)(rbase + xrow) * TT * DD + (t + 1) * DD + xcol];
        gemm_layer<5>(p0, S0, w0, b0r, gbuf, l15, q, nbase);
        __syncthreads();  // B1
        ew_layer(gme, c0, h0w, x1w);
        __syncthreads();  // B2
        gemm_layer<4>(p1, S12, w1, b1r, gbuf, l15, q, nbase);
        __syncthreads();  // B3
        ew_layer(gme, c1, h1w, x2w);
        __syncthreads();  // B4
        gemm_layer<4>(p2, S12, w2, b2r, gbuf, l15, q, nbase);
        __syncthreads();  // B5
        ew_layer(gme, c2, h2w, yw);   // h2 -> panel2 h-slot AND p0 y_prev slot
        __syncthreads();  // B6: h2 visible for FC
        if (wave == 0) {
            floatx4 fa = (floatx4){fbr, fbr, fbr, fbr};
#pragma unroll
            for (int kt = 0; kt < 2; ++kt) {
                half8 a = *(const half8*)(p2 + l15 * S12 + 64 + kt * 32 + q * 8);
                fa = __builtin_amdgcn_mfma_f32_16x16x32_f16(a, fw[kt], fa, 0, 0, 0);
            }
            if (l15 < 8) {
#pragma unroll
                for (int r = 0; r < 4; ++r)
                    out[(size_t)(rbase + q * 4 + r) * TT * DD + (size_t)t * DD + l15] = fa[r];
            }
        }
        // FC reads fenced from next ew2-write by B0'..B5'; other waves wait at B0'
    }
}

extern "C" void kernel_launch(void* const* d_in, const int* in_sizes, int n_in,
                              void* d_out, int out_size, void* d_ws, size_t ws_size,
                              hipStream_t stream) {
    const float* encx = (const float*)d_in[0];
    const float* decx = (const float*)d_in[1];
    const float* eW0i = (const float*)d_in[2];
    const float* eW0h = (const float*)d_in[3];
    const float* eb0  = (const float*)d_in[4];
    const float* eW1i = (const float*)d_in[5];
    const float* eW1h = (const float*)d_in[6];
    const float* eb1  = (const float*)d_in[7];
    const float* eW2i = (const float*)d_in[8];
    const float* eW2h = (const float*)d_in[9];
    const float* eb2  = (const float*)d_in[10];
    const float* dW0i = (const float*)d_in[11];
    const float* dW0h = (const float*)d_in[12];
    const float* db0  = (const float*)d_in[13];
    const float* dW1i = (const float*)d_in[14];
    const float* dW1h = (const float*)d_in[15];
    const float* db1  = (const float*)d_in[16];
    const float* dW2i = (const float*)d_in[17];
    const float* dW2h = (const float*)d_in[18];
    const float* db2  = (const float*)d_in[19];
    const float* fcW  = (const float*)d_in[20];
    const float* fcb  = (const float*)d_in[21];
    float* out = (float*)d_out;

    seq2seq_kernel<<<dim3(512), dim3(512), 0, stream>>>(
        encx, decx, eW0i, eW0h, eb0, eW1i, eW1h, eb1, eW2i, eW2h, eb2,
        dW0i, dW0h, db0, dW1i, dW1h, db1, dW2i, dW2h, db2, fcW, fcb, out);
}

// Round 3
// 4020.949 us; speedup vs baseline: 1.5781x; 1.0534x over previous
//
#include <hip/hip_runtime.h>

// Persistent seq2seq LSTM kernel for MI355X (gfx950).
// Design (v4 — gate-permuted columns + in-wave exchange, 3 barriers/step):
//  - 256 blocks x 512 threads (8 waves), M=32 rows/block (v1 tiling). Occupancy
//    lever is dead (unified-RF AGPR share blocks 2 blocks/CU); instead the
//    cross-wave gate exchange is removed structurally.
//  - Weight B-columns PERMUTED at load: wave w owns units [8w,8w+8) x 4 gates
//    (orig col n = gate*64 + unit). After MFMA, all 4 gates of a unit are in
//    one wave -> gate exchange is a wave-PRIVATE LDS strip (no barrier):
//    write 16 f32, lgkmcnt (compiler), read 4x ds_read_b128 (i,f,g,o contiguous).
//  - 3 barriers/step (one per layer, publishing h to next layer's panel), vs
//    v1's 6-7. WAR on h_prev removed by parity ping-pong slots:
//    read par 1-(t&1), write par t&1.
//  - Panels (f16, strides tuned for bank spread; all frag bases 16B-aligned):
//      p0 [32][232]: x(8)+pad | h0_par0(64)@32 | h0_par1(64)@96 | y(64)@160
//      p1 [32][200]: h0_in(64)@0 | h1_par0@64 | h1_par1@128
//      p2 [32][200]: h1_in(64)@0 | h2_par0@64 | h2_par1@128
//    wavebuf: 8 strips x [32 rows][36] f32 (gates at col nt*16+l15 == unit*4+gate).
//  - ew duty: lane -> unit 8*wave+(lane>>3), rows 8j+(lane&7) (conflict-free
//    b128 wavebuf reads). h f16 pair-packed across lane^8 (shfl) -> b32 stores.
//  - FC folded into next step's G0 phase (waves 0,1); final FC after loop.
//  - f16 storage + fp32 accumulate/state: same arithmetic as v1 (absmax ~1e-3).

#define TT   512
#define DD   8
#define HH   64
#define MM   32
#define S0   232   // p0 stride (f16): %8==0 (16B frags), 116 dw % 32 = 20 (spread)
#define S12  200   // p1/p2 stride: %8==0, 100 dw % 32 = 4 (spread)
#define WBS  36    // wavebuf row stride (f32): 16B-aligned reads, spread banks
#define WSTRIP (32 * WBS)

typedef _Float16 half8  __attribute__((ext_vector_type(8)));
typedef float    floatx4 __attribute__((ext_vector_type(4)));

__device__ __forceinline__ float sigf(float x) {
    return __builtin_amdgcn_rcpf(1.0f + __expf(-x));
}
__device__ __forceinline__ float tanhfast(float x) {
    return 1.0f - 2.0f * __builtin_amdgcn_rcpf(1.0f + __expf(2.0f * x));
}

// B-fragment loader, layers 1/2: k-panel [0,64)=Wih cols, [64,128)=Whh cols
__device__ __forceinline__ half8 ldfrag_l12(const float* Wih, const float* Whh,
                                            int n, int s) {
    const float* src = (s < HH) ? (Wih + n * HH + s) : (Whh + n * HH + (s - HH));
    half8 r;
#pragma unroll
    for (int j = 0; j < 8; ++j) r[j] = (_Float16)src[j];
    return r;
}

// B-fragment loader, layer 0 (enc kih=8, dec kih=72):
// k: [0,8)=Wih x-cols, [8,32)=zeros, [32,96)=Whh, [96,160)=Wih y-cols(8..71)
__device__ __forceinline__ half8 ldfrag_l0(const float* Wih, int kih,
                                           const float* Whh, int n, int s) {
    half8 r;
    const float* src = nullptr;
    if (s < 8)        src = Wih + n * kih + s;
    else if (s < 32)  src = nullptr;
    else if (s < 96)  src = Whh + n * HH + (s - 32);
    else              src = Wih + n * kih + (s - 88);
    if (src) {
#pragma unroll
        for (int j = 0; j < 8; ++j) r[j] = (_Float16)src[j];
    } else {
#pragma unroll
        for (int j = 0; j < 8; ++j) r[j] = (_Float16)0.f;
    }
    return r;
}

// Gate GEMM for one layer: acc(bias) += A(panel rows) * Wf; scatter preacts to
// this wave's PRIVATE wavebuf strip (col = nt*16+l15 == unit_lo*4+gate).
template <int KT, int KW>
__device__ __forceinline__ void gemm_layer(const _Float16* panel, int stride,
                                           const int (&aoff)[KT],
                                           const half8 (&wf)[KW][2],
                                           const float (&br)[2],
                                           float* wb, int l15, int q) {
    floatx4 acc[2][2];
#pragma unroll
    for (int mt = 0; mt < 2; ++mt)
#pragma unroll
        for (int nt = 0; nt < 2; ++nt)
            acc[mt][nt] = (floatx4){br[nt], br[nt], br[nt], br[nt]};
#pragma unroll
    for (int kt = 0; kt < KT; ++kt) {
        const _Float16* pk = panel + aoff[kt] + q * 8;
        half8 a0 = *(const half8*)(pk + l15 * stride);
        half8 a1 = *(const half8*)(pk + (16 + l15) * stride);
        acc[0][0] = __builtin_amdgcn_mfma_f32_16x16x32_f16(a0, wf[kt][0], acc[0][0], 0, 0, 0);
        acc[0][1] = __builtin_amdgcn_mfma_f32_16x16x32_f16(a0, wf[kt][1], acc[0][1], 0, 0, 0);
        acc[1][0] = __builtin_amdgcn_mfma_f32_16x16x32_f16(a1, wf[kt][0], acc[1][0], 0, 0, 0);
        acc[1][1] = __builtin_amdgcn_mfma_f32_16x16x32_f16(a1, wf[kt][1], acc[1][1], 0, 0, 0);
    }
    // C/D layout: col=lane&15, row=(lane>>4)*4+reg [HW-verified].
    // wavebuf col nt*16+l15 = (unit_lo<<2)|gate -- identity, no remap needed.
#pragma unroll
    for (int nt = 0; nt < 2; ++nt)
#pragma unroll
        for (int mt = 0; mt < 2; ++mt)
#pragma unroll
            for (int r = 0; r < 4; ++r)
                wb[(mt * 16 + q * 4 + r) * WBS + nt * 16 + l15] = acc[mt][nt][r];
}

// Elementwise cell update: this lane's unit (uu), rows 8j+(lane&7), j=0..3.
// Reads gate quads (b128) from own wave's strip; h f16 pair-packed via shfl^8
// into b32 stores by even-(lane>>3) lanes. pB may be null.
__device__ __forceinline__ void ew_layer(const float* wbr, int la7, float (&c)[4],
                                         _Float16* pA, int sA, int offA,
                                         _Float16* pB, int sB, int offB,
                                         int uu, bool loLane) {
#pragma unroll
    for (int j = 0; j < 4; ++j) {
        const int row = 8 * j + la7;
        floatx4 g = *(const floatx4*)(wbr + row * WBS);
        float iv = sigf(g[0]);
        float fv = sigf(g[1]);
        float gv = tanhfast(g[2]);
        float ov = sigf(g[3]);
        float cv = fv * c[j] + iv * gv;
        c[j] = cv;
        _Float16 hv = (_Float16)(ov * tanhfast(cv));
        unsigned short hb;
        __builtin_memcpy(&hb, &hv, 2);
        unsigned int mine = hb;
        unsigned int oth = (unsigned int)__shfl_xor((int)mine, 8, 64);
        if (loLane) {
            unsigned int word = mine | (oth << 16);
            *(unsigned int*)(pA + row * sA + offA + uu) = word;
            if (pB) *(unsigned int*)(pB + row * sB + offB + uu) = word;
        }
    }
}

__global__ __launch_bounds__(512, 1) void seq2seq_kernel(
    const float* __restrict__ encx, const float* __restrict__ decx,
    const float* __restrict__ eW0i, const float* __restrict__ eW0h, const float* __restrict__ eb0,
    const float* __restrict__ eW1i, const float* __restrict__ eW1h, const float* __restrict__ eb1,
    const float* __restrict__ eW2i, const float* __restrict__ eW2h, const float* __restrict__ eb2,
    const float* __restrict__ dW0i, const float* __restrict__ dW0h, const float* __restrict__ db0,
    const float* __restrict__ dW1i, const float* __restrict__ dW1h, const float* __restrict__ db1,
    const float* __restrict__ dW2i, const float* __restrict__ dW2h, const float* __restrict__ db2,
    const float* __restrict__ fcW, const float* __restrict__ fcb,
    float* __restrict__ out) {
    __shared__ _Float16 p0[MM * S0];
    __shared__ _Float16 p1[MM * S12];
    __shared__ _Float16 p2[MM * S12];
    __shared__ float wavebuf[8 * WSTRIP];

    const int tid  = threadIdx.x;
    const int lane = tid & 63;
    const int wave = tid >> 6;
    const int l15  = lane & 15;
    const int q    = lane >> 4;
    const int rbase = blockIdx.x * MM;

    // ew duty
    const int la7 = lane & 7;
    const int uu  = (wave << 3) + (lane >> 3);   // unit 0..63
    const bool loLane = (((lane >> 3) & 1) == 0);
    float* wb  = wavebuf + wave * WSTRIP;
    const float* wbr = wb + (lane >> 3) * 4;

    for (int i = tid; i < MM * S0;  i += 512) p0[i] = (_Float16)0.f;
    for (int i = tid; i < MM * S12; i += 512) p1[i] = (_Float16)0.f;
    for (int i = tid; i < MM * S12; i += 512) p2[i] = (_Float16)0.f;

    float c0[4] = {0, 0, 0, 0}, c1[4] = {0, 0, 0, 0}, c2[4] = {0, 0, 0, 0};

    // -------- encoder weight fragments (gate-permuted columns) --------
    half8 w0[5][2], w1[4][2], w2[4][2];
    float b0r[2], b1r[2], b2r[2];
#pragma unroll
    for (int nt = 0; nt < 2; ++nt) {
        const int cc = nt * 16 + l15;
        const int n = (cc & 3) * 64 + (wave << 3) + (cc >> 2);  // gate*64 + unit
#pragma unroll
        for (int kt = 0; kt < 3; ++kt) w0[kt][nt] = ldfrag_l0(eW0i, 8, eW0h, n, kt * 32 + q * 8);
#pragma unroll
        for (int kt = 0; kt < 4; ++kt) w1[kt][nt] = ldfrag_l12(eW1i, eW1h, n, kt * 32 + q * 8);
#pragma unroll
        for (int kt = 0; kt < 4; ++kt) w2[kt][nt] = ldfrag_l12(eW2i, eW2h, n, kt * 32 + q * 8);
        b0r[nt] = eb0[n]; b1r[nt] = eb1[n]; b2r[nt] = eb2[n];
    }

    const int xrow = tid >> 3;  // 0..31 (tid<256)
    const int xcol = tid & 7;
    float xr = 0.f;
    if (tid < 256) xr = encx[(size_t)(rbase + xrow) * TT * DD + xcol];

    __syncthreads();

    // ---------------- encoder loop ----------------
    for (int t = 0; t < TT; ++t) {
        const int wp = t & 1;        // write parity
        const int rp = 1 - wp;       // read parity
        if (tid < 256) p0[xrow * S0 + xcol] = (_Float16)xr;
        __syncthreads();  // B0: x + prev EW2 h2-writes visible
        if (tid < 256 && t + 1 < TT)
            xr = encx[(size_t)(rbase + xrow) * TT * DD + (t + 1) * DD + xcol];

        {   // P_A: G0 + in-wave exchange + EW0 + h0 writes
            const int aoff[3] = {0, 32 + 64 * rp, 64 + 64 * rp};
            gemm_layer<3>(p0, S0, aoff, w0, b0r, wb, l15, q);
            ew_layer(wbr, la7, c0, p0, S0, 32 + 64 * wp, p1, S12, 0, uu, loLane);
        }
        __syncthreads();  // B1: h0 visible
        {   // P_B: G1 + EW1
            const int aoff[4] = {0, 32, 64 + 64 * rp, 96 + 64 * rp};
            gemm_layer<4>(p1, S12, aoff, w1, b1r, wb, l15, q);
            ew_layer(wbr, la7, c1, p1, S12, 64 + 64 * wp, p2, S12, 0, uu, loLane);
        }
        __syncthreads();  // B2: h1 visible
        {   // P_C: G2 + EW2
            const int aoff[4] = {0, 32, 64 + 64 * rp, 96 + 64 * rp};
            gemm_layer<4>(p2, S12, aoff, w2, b2r, wb, l15, q);
            ew_layer(wbr, la7, c2, p2, S12, 64 + 64 * wp, (_Float16*)nullptr, 0, 0, uu, loLane);
        }
        // next-iter B0 fences h2 before its reader (G2 @ t+1)
    }

    __syncthreads();

    // -------- decoder weight fragments --------
#pragma unroll
    for (int nt = 0; nt < 2; ++nt) {
        const int cc = nt * 16 + l15;
        const int n = (cc & 3) * 64 + (wave << 3) + (cc >> 2);
#pragma unroll
        for (int kt = 0; kt < 5; ++kt) w0[kt][nt] = ldfrag_l0(dW0i, 72, dW0h, n, kt * 32 + q * 8);
#pragma unroll
        for (int kt = 0; kt < 4; ++kt) w1[kt][nt] = ldfrag_l12(dW1i, dW1h, n, kt * 32 + q * 8);
#pragma unroll
        for (int kt = 0; kt < 4; ++kt) w2[kt][nt] = ldfrag_l12(dW2i, dW2h, n, kt * 32 + q * 8);
        b0r[nt] = db0[n]; b1r[nt] = db1[n]; b2r[nt] = db2[n];
    }
    // FC fragments (waves 0,1 use them; cheap to load everywhere)
    half8 fw[2];
    const float fbr = (l15 < 8) ? fcb[l15] : 0.f;
#pragma unroll
    for (int kt = 0; kt < 2; ++kt) {
        half8 r;
        if (l15 < 8) {
            const float* s = fcW + l15 * HH + kt * 32 + q * 8;
#pragma unroll
            for (int j = 0; j < 8; ++j) r[j] = (_Float16)s[j];
        } else {
#pragma unroll
            for (int j = 0; j < 8; ++j) r[j] = (_Float16)0.f;
        }
        fw[kt] = r;
    }

    // y-slot (p0 @160) still zero from init; c,h carry over in regs/panels.
    if (tid < 256) xr = decx[(size_t)(rbase + xrow) * TT * DD + xcol];

    // ---------------- decoder loop ----------------
    for (int t = 0; t < TT; ++t) {
        const int wp = t & 1;
        const int rp = 1 - wp;
        if (tid < 256) p0[xrow * S0 + xcol] = (_Float16)xr;
        __syncthreads();  // B0: x, prev h2/y visible
        if (tid < 256 && t + 1 < TT)
            xr = decx[(size_t)(rbase + xrow) * TT * DD + (t + 1) * DD + xcol];

        {   // P_A: G0 (+ FC for step t-1 by waves 0,1) + EW0
            if (t > 0 && wave < 2) {
                const int fp = 1 - wp;   // (t-1)&1
                floatx4 fa = (floatx4){fbr, fbr, fbr, fbr};
#pragma unroll
                for (int kt = 0; kt < 2; ++kt) {
                    half8 a = *(const half8*)(p2 + (wave * 16 + l15) * S12 + 64 + 64 * fp + kt * 32 + q * 8);
                    fa = __builtin_amdgcn_mfma_f32_16x16x32_f16(a, fw[kt], fa, 0, 0, 0);
                }
                if (l15 < 8) {
#pragma unroll
                    for (int r = 0; r < 4; ++r)
                        out[(size_t)(rbase + wave * 16 + q * 4 + r) * TT * DD + (size_t)(t - 1) * DD + l15] = fa[r];
                }
            }
            const int aoff[5] = {0, 32 + 64 * rp, 64 + 64 * rp, 160, 192};
            gemm_layer<5>(p0, S0, aoff, w0, b0r, wb, l15, q);
            ew_layer(wbr, la7, c0, p0, S0, 32 + 64 * wp, p1, S12, 0, uu, loLane);
        }
        __syncthreads();  // B1
        {   // P_B: G1 + EW1
            const int aoff[4] = {0, 32, 64 + 64 * rp, 96 + 64 * rp};
            gemm_layer<4>(p1, S12, aoff, w1, b1r, wb, l15, q);
            ew_layer(wbr, la7, c1, p1, S12, 64 + 64 * wp, p2, S12, 0, uu, loLane);
        }
        __syncthreads();  // B2
        {   // P_C: G2 + EW2 (h2 -> p2 wp-slot AND y-slot p0@160)
            const int aoff[4] = {0, 32, 64 + 64 * rp, 96 + 64 * rp};
            gemm_layer<4>(p2, S12, aoff, w2, b2r, wb, l15, q);
            ew_layer(wbr, la7, c2, p2, S12, 64 + 64 * wp, p0, S0, 160, uu, loLane);
        }
        // next-iter B0 fences h2/y before readers
    }

    // final FC for t = TT-1
    __syncthreads();
    if (wave < 2) {
        const int fp = (TT - 1) & 1;
        floatx4 fa = (floatx4){fbr, fbr, fbr, fbr};
#pragma unroll
        for (int kt = 0; kt < 2; ++kt) {
            half8 a = *(const half8*)(p2 + (wave * 16 + l15) * S12 + 64 + 64 * fp + kt * 32 + q * 8);
            fa = __builtin_amdgcn_mfma_f32_16x16x32_f16(a, fw[kt], fa, 0, 0, 0);
        }
        if (l15 < 8) {
#pragma unroll
            for (int r = 0; r < 4; ++r)
                out[(size_t)(rbase + wave * 16 + q * 4 + r) * TT * DD + (size_t)(TT - 1) * DD + l15] = fa[r];
        }
    }
}

extern "C" void kernel_launch(void* const* d_in, const int* in_sizes, int n_in,
                              void* d_out, int out_size, void* d_ws, size_t ws_size,
                              hipStream_t stream) {
    const float* encx = (const float*)d_in[0];
    const float* decx = (const float*)d_in[1];
    const float* eW0i = (const float*)d_in[2];
    const float* eW0h = (const float*)d_in[3];
    const float* eb0  = (const float*)d_in[4];
    const float* eW1i = (const float*)d_in[5];
    const float* eW1h = (const float*)d_in[6];
    const float* eb1  = (const float*)d_in[7];
    const float* eW2i = (const float*)d_in[8];
    const float* eW2h = (const float*)d_in[9];
    const float* eb2  = (const float*)d_in[10];
    const float* dW0i = (const float*)d_in[11];
    const float* dW0h = (const float*)d_in[12];
    const float* db0  = (const float*)d_in[13];
    const float* dW1i = (const float*)d_in[14];
    const float* dW1h = (const float*)d_in[15];
    const float* db1  = (const float*)d_in[16];
    const float* dW2i = (const float*)d_in[17];
    const float* dW2h = (const float*)d_in[18];
    const float* db2  = (const float*)d_in[19];
    const float* fcW  = (const float*)d_in[20];
    const float* fcb  = (const float*)d_in[21];
    float* out = (float*)d_out;

    seq2seq_kernel<<<dim3(256), dim3(512), 0, stream>>>(
        encx, decx, eW0i, eW0h, eb0, eW1i, eW1h, eb1, eW2i, eW2h, eb2,
        dW0i, dW0h, db0, dW1i, dW1h, db1, dW2i, dW2h, db2, fcW, fcb, out);
}

// Round 4
// 3175.694 us; speedup vs baseline: 1.9981x; 1.2662x over previous
//
#include <hip/hip_runtime.h>

// Persistent seq2seq LSTM kernel for MI355X (gfx950).
// Design (v5 — 16 waves/block, 4 waves/SIMD):
//  - 256 blocks x 1024 threads (16 waves), M=32 rows/block. v1/v3/v4 showed the
//    limiter is per-SIMD issue + latency at 2 waves/SIMD (barrier topology was
//    insensitive: 3675/4236/4021 us). 16 waves needs <=128 VGPR/thread: each
//    wave owns 16 gate cols -> weight frags = 13 half8 = 52 VGPR (was 104).
//  - Gate-permuted weight columns (v4): wave w owns units [4w,4w+4) x 4 gates
//    (orig col n = gate*64 + unit). All 4 gates of a unit land in one wave ->
//    wave-private LDS strip exchange, no barrier. 3 barriers/step.
//  - exp2-folding: sigmoid/tanh computed as rcp(1+exp2(y)) with the gate scale
//    (-log2e for i,f,o; +2log2e for g) folded into the one-time f32->f16 weight
//    + bias conversion. Removes one v_mul per transcendental.
//  - ew duty: lane -> row=lane&31, units u0=4w+2*(lane>>5)+{0,1} (adjacent) ->
//    h pair packed in-thread (no shfl), one b32 store per destination panel.
//  - Panels (f16): p0 [32][232]: x(8)+pad | h0_p0@32 | h0_p1@96 | y@160
//                  p1/p2 [32][200]: in@0 | h_p0@64 | h_p1@128
//    wavebuf: 16 strips x [32][20] f32 (row-conflict-free b128 reads/writes).
//    Parity ping-pong (read 1-(t&1), write t&1) removes WAR on h_prev.
//  - FC folded into next step's G0 phase (waves 0,1); final FC after loop.
//  - f16 storage + fp32 accumulate/state.

#define TT   512
#define DD   8
#define HH   64
#define MM   32
#define S0   232   // p0 stride (f16): %8==0 (16B frags), dw%32=20 -> bank spread
#define S12  200   // p1/p2 stride: %8==0, dw%32=4 -> bank spread
#define WBS  20    // wavebuf row stride (f32): 16B-aligned, 20%32 spreads banks
#define WSTRIP (32 * WBS)

#define NLOG2E  -1.442695041f   // -log2(e): folded into i,f,o columns
#define P2LOG2E  2.885390082f   // +2log2(e): folded into g columns

typedef _Float16 half8  __attribute__((ext_vector_type(8)));
typedef _Float16 half2v __attribute__((ext_vector_type(2)));
typedef float    floatx4 __attribute__((ext_vector_type(4)));

// sigmoid(x) with y = -x*log2e pre-folded: 1/(1+2^y)
__device__ __forceinline__ float sig2(float y) {
    return __builtin_amdgcn_rcpf(1.0f + __builtin_amdgcn_exp2f(y));
}
// tanh(x) with y = 2x*log2e pre-folded: 1 - 2/(1+2^y)
__device__ __forceinline__ float th2(float y) {
    return 1.0f - 2.0f * __builtin_amdgcn_rcpf(1.0f + __builtin_amdgcn_exp2f(y));
}

// B-fragment loader, layers 1/2: k-panel [0,64)=Wih cols, [64,128)=Whh cols
__device__ __forceinline__ half8 ldfrag_l12(const float* Wih, const float* Whh,
                                            int n, int s, float sc) {
    const float* src = (s < HH) ? (Wih + n * HH + s) : (Whh + n * HH + (s - HH));
    half8 r;
#pragma unroll
    for (int j = 0; j < 8; ++j) r[j] = (_Float16)(src[j] * sc);
    return r;
}

// B-fragment loader, layer 0 (enc kih=8, dec kih=72):
// k: [0,8)=Wih x-cols, [8,32)=zeros, [32,96)=Whh, [96,160)=Wih y-cols(8..71)
__device__ __forceinline__ half8 ldfrag_l0(const float* Wih, int kih,
                                           const float* Whh, int n, int s,
                                           float sc) {
    half8 r;
    const float* src = nullptr;
    if (s < 8)        src = Wih + n * kih + s;
    else if (s < 32)  src = nullptr;
    else if (s < 96)  src = Whh + n * HH + (s - 32);
    else              src = Wih + n * kih + (s - 88);
    if (src) {
#pragma unroll
        for (int j = 0; j < 8; ++j) r[j] = (_Float16)(src[j] * sc);
    } else {
#pragma unroll
        for (int j = 0; j < 8; ++j) r[j] = (_Float16)0.f;
    }
    return r;
}

// Gate GEMM, one layer: 16 cols/wave (1 n-tile, 2 m-tiles). acc(bias-init) +=
// A(panel) * wf; scatter preacts to this wave's PRIVATE wavebuf strip.
// Scatter bank check: addr=(mt*16+q*4+r)*20+l15 -> 2-way max (free).
template <int KT, int KW>
__device__ __forceinline__ void gemm_layer(const _Float16* panel, int stride,
                                           const int (&aoff)[KT],
                                           const half8 (&wf)[KW], float br,
                                           float* wb, int l15, int q) {
    floatx4 acc[2];
    acc[0] = (floatx4){br, br, br, br};
    acc[1] = (floatx4){br, br, br, br};
#pragma unroll
    for (int kt = 0; kt < KT; ++kt) {
        const _Float16* pk = panel + aoff[kt] + q * 8;
        half8 a0 = *(const half8*)(pk + l15 * stride);
        half8 a1 = *(const half8*)(pk + (16 + l15) * stride);
        acc[0] = __builtin_amdgcn_mfma_f32_16x16x32_f16(a0, wf[kt], acc[0], 0, 0, 0);
        acc[1] = __builtin_amdgcn_mfma_f32_16x16x32_f16(a1, wf[kt], acc[1], 0, 0, 0);
    }
    // C/D layout: col=lane&15, row=(lane>>4)*4+reg [HW-verified].
    // wavebuf col l15 = (du<<2)|gate (du = unit - 4*wave) -- identity map.
#pragma unroll
    for (int mt = 0; mt < 2; ++mt)
#pragma unroll
        for (int r = 0; r < 4; ++r)
            wb[(mt * 16 + q * 4 + r) * WBS + l15] = acc[mt][r];
}

// Elementwise cell update: this thread's 2 ADJACENT units (u0,u0+1) of one row.
// Reads 2 gate quads (b128, conflict-free) from own wave's strip; writes the
// f16 h-pair as one b32 store per destination. dB may be null.
__device__ __forceinline__ void ew_layer(const float* wbr, float (&c)[2],
                                         _Float16* dA, _Float16* dB) {
    floatx4 g0 = *(const floatx4*)(wbr);
    floatx4 g1 = *(const floatx4*)(wbr + 4);
    float h0, h1;
    {
        float iv = sig2(g0[0]);
        float fv = sig2(g0[1]);
        float gv = th2(g0[2]);
        float ov = sig2(g0[3]);
        float cv = fv * c[0] + iv * gv;
        c[0] = cv;
        h0 = ov * th2(cv * P2LOG2E);
    }
    {
        float iv = sig2(g1[0]);
        float fv = sig2(g1[1]);
        float gv = th2(g1[2]);
        float ov = sig2(g1[3]);
        float cv = fv * c[1] + iv * gv;
        c[1] = cv;
        h1 = ov * th2(cv * P2LOG2E);
    }
    half2v hp;
    hp[0] = (_Float16)h0;
    hp[1] = (_Float16)h1;
    *(half2v*)dA = hp;
    if (dB) *(half2v*)dB = hp;
}

__global__ __launch_bounds__(1024, 1) void seq2seq_kernel(
    const float* __restrict__ encx, const float* __restrict__ decx,
    const float* __restrict__ eW0i, const float* __restrict__ eW0h, const float* __restrict__ eb0,
    const float* __restrict__ eW1i, const float* __restrict__ eW1h, const float* __restrict__ eb1,
    const float* __restrict__ eW2i, const float* __restrict__ eW2h, const float* __restrict__ eb2,
    const float* __restrict__ dW0i, const float* __restrict__ dW0h, const float* __restrict__ db0,
    const float* __restrict__ dW1i, const float* __restrict__ dW1h, const float* __restrict__ db1,
    const float* __restrict__ dW2i, const float* __restrict__ dW2h, const float* __restrict__ db2,
    const float* __restrict__ fcW, const float* __restrict__ fcb,
    float* __restrict__ out) {
    __shared__ _Float16 p0[MM * S0];
    __shared__ _Float16 p1[MM * S12];
    __shared__ _Float16 p2[MM * S12];
    __shared__ float wavebuf[16 * WSTRIP];

    const int tid  = threadIdx.x;
    const int lane = tid & 63;
    const int wave = tid >> 6;           // 0..15
    const int l15  = lane & 15;
    const int q    = lane >> 4;
    const int rbase = blockIdx.x * MM;

    // weight column for this lane's single n-tile (gate-permuted)
    const int gate = l15 & 3;
    const int n = gate * 64 + (wave << 2) + (l15 >> 2);
    const float wsc = (gate == 2) ? P2LOG2E : NLOG2E;

    // ew duty: row = lane&31, adjacent unit pair u0,u0+1
    const int erow  = lane & 31;
    const int upair = lane >> 5;
    const int u0 = (wave << 2) + (upair << 1);
    float* wb = wavebuf + wave * WSTRIP;
    const float* wbr = wb + erow * WBS + (upair << 3);

    for (int i = tid; i < MM * S0;  i += 1024) p0[i] = (_Float16)0.f;
    for (int i = tid; i < MM * S12; i += 1024) p1[i] = (_Float16)0.f;
    for (int i = tid; i < MM * S12; i += 1024) p2[i] = (_Float16)0.f;

    float c0[2] = {0, 0}, c1[2] = {0, 0}, c2[2] = {0, 0};

    // -------- encoder weight fragments (scaled, permuted) --------
    half8 w0[5], w1[4], w2[4];
    float b0r, b1r, b2r;
#pragma unroll
    for (int kt = 0; kt < 3; ++kt) w0[kt] = ldfrag_l0(eW0i, 8, eW0h, n, kt * 32 + q * 8, wsc);
#pragma unroll
    for (int kt = 0; kt < 4; ++kt) w1[kt] = ldfrag_l12(eW1i, eW1h, n, kt * 32 + q * 8, wsc);
#pragma unroll
    for (int kt = 0; kt < 4; ++kt) w2[kt] = ldfrag_l12(eW2i, eW2h, n, kt * 32 + q * 8, wsc);
    b0r = eb0[n] * wsc; b1r = eb1[n] * wsc; b2r = eb2[n] * wsc;

    const int xrow = tid >> 3;  // 0..31 (tid<256)
    const int xcol = tid & 7;
    float xr = 0.f;
    if (tid < 256) xr = encx[(size_t)(rbase + xrow) * TT * DD + xcol];

    // h-write bases (parity offset added at use)
    _Float16* h0A = p0 + erow * S0 + 32 + u0;
    _Float16* h0B = p1 + erow * S12 + u0;
    _Float16* h1A = p1 + erow * S12 + 64 + u0;
    _Float16* h1B = p2 + erow * S12 + u0;
    _Float16* h2A = p2 + erow * S12 + 64 + u0;
    _Float16* yB  = p0 + erow * S0 + 160 + u0;

    __syncthreads();

    // ---------------- encoder loop ----------------
    for (int t = 0; t < TT; ++t) {
        const int wp = t & 1;
        const int rp = 1 - wp;
        if (tid < 256) p0[xrow * S0 + xcol] = (_Float16)xr;
        __syncthreads();  // B0: x + prev EW2 h2-writes visible
        if (tid < 256 && t + 1 < TT)
            xr = encx[(size_t)(rbase + xrow) * TT * DD + (t + 1) * DD + xcol];

        {   // P_A: G0 + in-wave exchange + EW0
            const int aoff[3] = {0, 32 + 64 * rp, 64 + 64 * rp};
            gemm_layer<3, 5>(p0, S0, aoff, w0, b0r, wb, l15, q);
            ew_layer(wbr, c0, h0A + 64 * wp, h0B);
        }
        __syncthreads();  // B1: h0 visible
        {   // P_B: G1 + EW1
            const int aoff[4] = {0, 32, 64 + 64 * rp, 96 + 64 * rp};
            gemm_layer<4, 4>(p1, S12, aoff, w1, b1r, wb, l15, q);
            ew_layer(wbr, c1, h1A + 64 * wp, h1B);
        }
        __syncthreads();  // B2: h1 visible
        {   // P_C: G2 + EW2
            const int aoff[4] = {0, 32, 64 + 64 * rp, 96 + 64 * rp};
            gemm_layer<4, 4>(p2, S12, aoff, w2, b2r, wb, l15, q);
            ew_layer(wbr, c2, h2A + 64 * wp, (_Float16*)nullptr);
        }
        // next-iter B0 fences h2 before its reader (G2 @ t+1)
    }

    __syncthreads();

    // -------- decoder weight fragments --------
#pragma unroll
    for (int kt = 0; kt < 5; ++kt) w0[kt] = ldfrag_l0(dW0i, 72, dW0h, n, kt * 32 + q * 8, wsc);
#pragma unroll
    for (int kt = 0; kt < 4; ++kt) w1[kt] = ldfrag_l12(dW1i, dW1h, n, kt * 32 + q * 8, wsc);
#pragma unroll
    for (int kt = 0; kt < 4; ++kt) w2[kt] = ldfrag_l12(dW2i, dW2h, n, kt * 32 + q * 8, wsc);
    b0r = db0[n] * wsc; b1r = db1[n] * wsc; b2r = db2[n] * wsc;

    // FC fragments (unscaled; used by waves 0,1)
    half8 fw[2];
    const float fbr = (l15 < 8) ? fcb[l15] : 0.f;
#pragma unroll
    for (int kt = 0; kt < 2; ++kt) {
        half8 r;
        if (l15 < 8) {
            const float* s = fcW + l15 * HH + kt * 32 + q * 8;
#pragma unroll
            for (int j = 0; j < 8; ++j) r[j] = (_Float16)s[j];
        } else {
#pragma unroll
            for (int j = 0; j < 8; ++j) r[j] = (_Float16)0.f;
        }
        fw[kt] = r;
    }

    // y-slot (p0@160) still zero from init
    if (tid < 256) xr = decx[(size_t)(rbase + xrow) * TT * DD + xcol];

    // ---------------- decoder loop ----------------
    for (int t = 0; t < TT; ++t) {
        const int wp = t & 1;
        const int rp = 1 - wp;
        if (tid < 256) p0[xrow * S0 + xcol] = (_Float16)xr;
        __syncthreads();  // B0: x, prev h2/y visible
        if (tid < 256 && t + 1 < TT)
            xr = decx[(size_t)(rbase + xrow) * TT * DD + (t + 1) * DD + xcol];

        {   // P_A: (FC for step t-1 by waves 0,1) + G0 + EW0
            if (t > 0 && wave < 2) {
                const int fp = 1 - wp;   // (t-1)&1
                floatx4 fa = (floatx4){fbr, fbr, fbr, fbr};
#pragma unroll
                for (int kt = 0; kt < 2; ++kt) {
                    half8 a = *(const half8*)(p2 + (wave * 16 + l15) * S12 + 64 + 64 * fp + kt * 32 + q * 8);
                    fa = __builtin_amdgcn_mfma_f32_16x16x32_f16(a, fw[kt], fa, 0, 0, 0);
                }
                if (l15 < 8) {
#pragma unroll
                    for (int r = 0; r < 4; ++r)
                        out[(size_t)(rbase + wave * 16 + q * 4 + r) * TT * DD + (size_t)(t - 1) * DD + l15] = fa[r];
                }
            }
            const int aoff[5] = {0, 32 + 64 * rp, 64 + 64 * rp, 160, 192};
            gemm_layer<5, 5>(p0, S0, aoff, w0, b0r, wb, l15, q);
            ew_layer(wbr, c0, h0A + 64 * wp, h0B);
        }
        __syncthreads();  // B1
        {   // P_B: G1 + EW1
            const int aoff[4] = {0, 32, 64 + 64 * rp, 96 + 64 * rp};
            gemm_layer<4, 4>(p1, S12, aoff, w1, b1r, wb, l15, q);
            ew_layer(wbr, c1, h1A + 64 * wp, h1B);
        }
        __syncthreads();  // B2
        {   // P_C: G2 + EW2 (h2 -> p2 wp-slot AND y-slot p0@160)
            const int aoff[4] = {0, 32, 64 + 64 * rp, 96 + 64 * rp};
            gemm_layer<4, 4>(p2, S12, aoff, w2, b2r, wb, l15, q);
            ew_layer(wbr, c2, h2A + 64 * wp, yB);
        }
        // next-iter B0 fences h2/y before readers
    }

    // final FC for t = TT-1
    __syncthreads();
    if (wave < 2) {
        const int fp = (TT - 1) & 1;
        floatx4 fa = (floatx4){fbr, fbr, fbr, fbr};
#pragma unroll
        for (int kt = 0; kt < 2; ++kt) {
            half8 a = *(const half8*)(p2 + (wave * 16 + l15) * S12 + 64 + 64 * fp + kt * 32 + q * 8);
            fa = __builtin_amdgcn_mfma_f32_16x16x32_f16(a, fw[kt], fa, 0, 0, 0);
        }
        if (l15 < 8) {
#pragma unroll
            for (int r = 0; r < 4; ++r)
                out[(size_t)(rbase + wave * 16 + q * 4 + r) * TT * DD + (size_t)(TT - 1) * DD + l15] = fa[r];
        }
    }
}

extern "C" void kernel_launch(void* const* d_in, const int* in_sizes, int n_in,
                              void* d_out, int out_size, void* d_ws, size_t ws_size,
                              hipStream_t stream) {
    const float* encx = (const float*)d_in[0];
    const float* decx = (const float*)d_in[1];
    const float* eW0i = (const float*)d_in[2];
    const float* eW0h = (const float*)d_in[3];
    const float* eb0  = (const float*)d_in[4];
    const float* eW1i = (const float*)d_in[5];
    const float* eW1h = (const float*)d_in[6];
    const float* eb1  = (const float*)d_in[7];
    const float* eW2i = (const float*)d_in[8];
    const float* eW2h = (const float*)d_in[9];
    const float* eb2  = (const float*)d_in[10];
    const float* dW0i = (const float*)d_in[11];
    const float* dW0h = (const float*)d_in[12];
    const float* db0  = (const float*)d_in[13];
    const float* dW1i = (const float*)d_in[14];
    const float* dW1h = (const float*)d_in[15];
    const float* db1  = (const float*)d_in[16];
    const float* dW2i = (const float*)d_in[17];
    const float* dW2h = (const float*)d_in[18];
    const float* db2  = (const float*)d_in[19];
    const float* fcW  = (const float*)d_in[20];
    const float* fcb  = (const float*)d_in[21];
    float* out = (float*)d_out;

    seq2seq_kernel<<<dim3(256), dim3(1024), 0, stream>>>(
        encx, decx, eW0i, eW0h, eb0, eW1i, eW1h, eb1, eW2i, eW2h, eb2,
        dW0i, dW0h, db0, dW1i, dW1h, db1, dW2i, dW2h, db2, fcW, fcb, out);
}